// Round 15
// baseline (228.560 us; speedup 1.0000x reference)
//
#include <hip/hip_runtime.h>
#include <math.h>

#define NTOK 16384
#define H 4096
#define NE 256
#define EPS_E 1.2e-5f
#define EPS_G 2.4e-5f
#define FIXCAP 1024
#define FLAGCAP 8192

typedef __attribute__((ext_vector_type(8))) short short8;
typedef __attribute__((ext_vector_type(4))) float f32x4;

__device__ __forceinline__ unsigned short f2bf(float x) {
    union { float f; unsigned u; } v; v.f = x;
    unsigned r = v.u + 0x7FFF + ((v.u >> 16) & 1);
    return (unsigned short)(r >> 16);
}
__device__ __forceinline__ float bf2f(unsigned short h) {
    union { float f; unsigned u; } v; v.u = ((unsigned)h) << 16;
    return v.f;
}

__global__ __launch_bounds__(256)
void split_w(const float* __restrict__ W, unsigned short* __restrict__ whi,
             unsigned short* __restrict__ wlo, int* __restrict__ ws)
{
    if (blockIdx.x == 0 && threadIdx.x == 0) ws[0] = 0;
    const int i = (blockIdx.x * 256 + threadIdx.x) * 4;
    float4 w4 = *(const float4*)(W + i);
    const float wv[4] = {w4.x, w4.y, w4.z, w4.w};
    ushort4 hh, ll;
    unsigned short* hp = (unsigned short*)&hh;
    unsigned short* lp = (unsigned short*)&ll;
    #pragma unroll
    for (int j = 0; j < 4; ++j) {
        unsigned short h = f2bf(wv[j]);
        hp[j] = h;
        lp[j] = f2bf(wv[j] - bf2f(h));
    }
    *(ushort4*)(whi + i) = hh;
    *(ushort4*)(wlo + i) = ll;
}

// ============ Stage 1 (split-K): BM=128 x BN=128 x Khalf=2048, 64KB, 2 blocks/CU ============
__global__ __launch_bounds__(256, 2)
void gemm3sk(const float* __restrict__ X, const unsigned short* __restrict__ Whi,
             const unsigned short* __restrict__ Wlo,
             float* __restrict__ logits0, float* __restrict__ logits1)
{
    __shared__ __align__(16) unsigned short smem[32768];  // 64 KB
    unsigned short* Ah = smem;              // [128][64] 16KB, XOR-swizzled
    unsigned short* Al = smem + 8192;
    unsigned short* Bh = smem + 16384;      // [128][64]
    unsigned short* Bl = smem + 24576;

    const int t = threadIdx.x;
    const int lane = t & 63;
    const int w = t >> 6;                   // 0..3
    const int wm = w >> 1, wn = w & 1;      // wave tile 64x64
    const int fr = lane & 15, fq = lane >> 4;

    const int G = (int)gridDim.x;           // 512, %8==0
    const int swz = (blockIdx.x & 7) * (G >> 3) + (blockIdx.x >> 3);
    const int kh = swz & 1;
    const int nb = (swz >> 1) & 1;
    const int mb = swz >> 2;
    const int mloc = mb * 128;
    const int e0 = nb * 128;
    const int kbase = kh * 32;              // k-step base (BK=64, 32 steps per half)

    f32x4 acc[4][4];
    #pragma unroll
    for (int a = 0; a < 4; ++a)
        #pragma unroll
        for (int b = 0; b < 4; ++b) acc[a][b] = (f32x4){0.f, 0.f, 0.f, 0.f};

    // A staging: thread t -> row t>>1 (0..127), 32-float half (t&1)
    const int ar = t >> 1;
    const int ah2 = t & 1;
    const float* gxa = X + (size_t)(mloc + ar) * H + ah2 * 32;

    // B staging via global_load_lds (linear dest, pre-swizzled source) — R8-proven map
    const int blr = lane >> 3;
    const int bsrc = (lane & 7) ^ blr;
    const unsigned short* gbh = Whi + (size_t)(e0 + w * 8 + blr) * H + bsrc * 8;
    const unsigned short* gbl = Wlo + (size_t)(e0 + w * 8 + blr) * H + bsrc * 8;

    float4 xr0, xr1, xr2, xr3, xr4, xr5, xr6, xr7;
    auto loadX = [&](int kt) {
        const float* p = gxa + (size_t)kt * 64;
        xr0 = *(const float4*)p;        xr1 = *(const float4*)(p + 4);
        xr2 = *(const float4*)(p + 8);  xr3 = *(const float4*)(p + 12);
        xr4 = *(const float4*)(p + 16); xr5 = *(const float4*)(p + 20);
        xr6 = *(const float4*)(p + 24); xr7 = *(const float4*)(p + 28);
    };

    loadX(kbase);   // 8 X loads in flight

    #pragma unroll 1
    for (int ks = 0; ks < 32; ++ks) {
        const int kt = kbase + ks;
        // all waves done reading previous tile
        __builtin_amdgcn_sched_barrier(0);
        __builtin_amdgcn_s_barrier();
        __builtin_amdgcn_sched_barrier(0);
        // issue B(kt): 8 gload_lds/wave  [outstanding: 8 X old + 8 B new]
        const size_t k0 = (size_t)kt * 64;
        #pragma unroll
        for (int i = 0; i < 4; ++i) {
            __builtin_amdgcn_global_load_lds(
                (const __attribute__((address_space(1))) void*)(gbh + (size_t)(32 * i) * H + k0),
                (__attribute__((address_space(3))) void*)&Bh[(w * 8 + 32 * i) * 64], 16, 0, 0);
            __builtin_amdgcn_global_load_lds(
                (const __attribute__((address_space(1))) void*)(gbl + (size_t)(32 * i) * H + k0),
                (__attribute__((address_space(3))) void*)&Bl[(w * 8 + 32 * i) * 64], 16, 0, 0);
        }
        __builtin_amdgcn_sched_barrier(0);
        // X(kt) landed (drain 8 oldest; B stays in flight)
        asm volatile("s_waitcnt vmcnt(8)" ::: "memory");
        __builtin_amdgcn_sched_barrier(0);
        // split X(kt): 32 floats -> 4 hi/lo short8 pairs, swizzled A writes
        {
            const float xf[32] = {xr0.x, xr0.y, xr0.z, xr0.w, xr1.x, xr1.y, xr1.z, xr1.w,
                                  xr2.x, xr2.y, xr2.z, xr2.w, xr3.x, xr3.y, xr3.z, xr3.w,
                                  xr4.x, xr4.y, xr4.z, xr4.w, xr5.x, xr5.y, xr5.z, xr5.w,
                                  xr6.x, xr6.y, xr6.z, xr6.w, xr7.x, xr7.y, xr7.z, xr7.w};
            #pragma unroll
            for (int c = 0; c < 4; ++c) {
                short8 h8, l8;
                #pragma unroll
                for (int j = 0; j < 8; ++j) {
                    union { float f; unsigned u; } uu; uu.f = xf[c * 8 + j];
                    union { unsigned u; float f; } hh; hh.u = uu.u & 0xFFFF0000u;
                    union { float f; unsigned u; } ll; ll.f = xf[c * 8 + j] - hh.f;
                    h8[j] = (short)(uu.u >> 16);
                    l8[j] = (short)(ll.u >> 16);
                }
                const int cc = ah2 * 4 + c;
                const int pos = (cc ^ (ar & 7)) * 8;
                *(short8*)&Ah[ar * 64 + pos] = h8;
                *(short8*)&Al[ar * 64 + pos] = l8;
            }
        }
        // prefetch X(kt+1)  [outstanding: 8 B old + 8 X new]
        loadX(ks + 1 < 32 ? kt + 1 : kt);
        __builtin_amdgcn_sched_barrier(0);
        // B(kt) landed (keep 8 X in flight); A writes visible
        asm volatile("s_waitcnt vmcnt(8) lgkmcnt(0)" ::: "memory");
        __builtin_amdgcn_sched_barrier(0);
        __builtin_amdgcn_s_barrier();
        __builtin_amdgcn_sched_barrier(0);
        // compute: 96 MFMAs/wave (wave tile 64x64)
        #pragma unroll
        for (int kk = 0; kk < 2; ++kk) {
            short8 ah[4], al[4], bh[4], bl[4];
            #pragma unroll
            for (int mt = 0; mt < 4; ++mt) {
                const int r = wm * 64 + mt * 16 + fr;
                const int pos = ((kk * 4 + fq) ^ (r & 7)) * 8;
                ah[mt] = *(const short8*)&Ah[r * 64 + pos];
                al[mt] = *(const short8*)&Al[r * 64 + pos];
            }
            #pragma unroll
            for (int nt = 0; nt < 4; ++nt) {
                const int r = wn * 64 + nt * 16 + fr;
                const int pos = ((kk * 4 + fq) ^ (r & 7)) * 8;
                bh[nt] = *(const short8*)&Bh[r * 64 + pos];
                bl[nt] = *(const short8*)&Bl[r * 64 + pos];
            }
            #pragma unroll
            for (int mt = 0; mt < 4; ++mt)
                #pragma unroll
                for (int nt = 0; nt < 4; ++nt)
                    acc[mt][nt] = __builtin_amdgcn_mfma_f32_16x16x32_bf16(ah[mt], bh[nt], acc[mt][nt], 0, 0, 0);
            #pragma unroll
            for (int mt = 0; mt < 4; ++mt)
                #pragma unroll
                for (int nt = 0; nt < 4; ++nt)
                    acc[mt][nt] = __builtin_amdgcn_mfma_f32_16x16x32_bf16(ah[mt], bl[nt], acc[mt][nt], 0, 0, 0);
            #pragma unroll
            for (int mt = 0; mt < 4; ++mt)
                #pragma unroll
                for (int nt = 0; nt < 4; ++nt)
                    acc[mt][nt] = __builtin_amdgcn_mfma_f32_16x16x32_bf16(al[mt], bh[nt], acc[mt][nt], 0, 0, 0);
        }
    }
    asm volatile("" :: "v"(xr0.x), "v"(xr1.x), "v"(xr2.x), "v"(xr3.x),
                       "v"(xr4.x), "v"(xr5.x), "v"(xr6.x), "v"(xr7.x));
    asm volatile("s_waitcnt vmcnt(0) lgkmcnt(0)" ::: "memory");

    // store partial logits to this half's buffer
    float* lgout = kh ? logits1 : logits0;
    #pragma unroll
    for (int mt = 0; mt < 4; ++mt)
        #pragma unroll
        for (int nt = 0; nt < 4; ++nt)
            #pragma unroll
            for (int r = 0; r < 4; ++r)
                lgout[(size_t)(mloc + wm * 64 + mt * 16 + fq * 4 + r) * NE +
                      (e0 + wn * 64 + nt * 16 + fr)] = acc[mt][nt][r];
}

// ============ Stage 2 (split-K): routing from l0+l1 (verified epilogue) ============
__global__ __launch_bounds__(256)
void route2(const float* __restrict__ l0, const float* __restrict__ l1,
            const float* __restrict__ bias, float* __restrict__ out,
            int* __restrict__ ws, int cap)
{
    const int t = threadIdx.x, lane = t & 63, wv = t >> 6;
    const float4 bf4 = *(const float4*)(bias + lane * 4);
    const float bfa[4] = {bf4.x, bf4.y, bf4.z, bf4.w};

    #pragma unroll 1
    for (int tt = 0; tt < 8; ++tt) {
        const int n = blockIdx.x * 32 + wv * 8 + tt;
        const float4 ga = *(const float4*)&l0[(size_t)n * NE + lane * 4];
        const float4 gb = *(const float4*)&l1[(size_t)n * NE + lane * 4];
        const float lga[4] = {ga.x + gb.x, ga.y + gb.y, ga.z + gb.z, ga.w + gb.w};
        float s[4], sc[4];
        #pragma unroll
        for (int i = 0; i < 4; ++i) {
            s[i] = 1.f / (1.f + expf(-lga[i]));
            sc[i] = s[i] + bfa[i];
        }
        float a1 = fmaxf(sc[0], sc[1]), a2 = fminf(sc[0], sc[1]);
        float b1 = fmaxf(sc[2], sc[3]), b2 = fminf(sc[2], sc[3]);
        float t1 = fmaxf(a1, b1);
        float t2 = fmaxf(fminf(a1, b1), fmaxf(a2, b2));
        #pragma unroll
        for (int off = 1; off <= 4; off <<= 1) {
            float o1 = __shfl_xor(t1, off, 64);
            float o2 = __shfl_xor(t2, off, 64);
            float n1 = fmaxf(t1, o1);
            float n2 = fmaxf(fminf(t1, o1), fmaxf(t2, o2));
            t1 = n1; t2 = n2;
        }
        const float gsum = t1 + t2;
        float gsv[8];
        #pragma unroll
        for (int g = 0; g < 8; ++g) gsv[g] = __shfl(gsum, g * 8, 64);

        float minsel = 3e38f, maxuns = -3e38f;
        bool sel = false;
        const int myg = lane >> 3;
        #pragma unroll
        for (int g = 0; g < 8; ++g) {
            int cg = 0;
            #pragma unroll
            for (int g2 = 0; g2 < 8; ++g2)
                cg += (gsv[g2] > gsv[g] || (gsv[g2] == gsv[g] && g2 < g)) ? 1 : 0;
            const bool sg = (cg < 4);
            if (sg) minsel = fminf(minsel, gsv[g]); else maxuns = fmaxf(maxuns, gsv[g]);
            if (myg == g) sel = sg;
        }
        bool flag = (minsel - maxuns) < EPS_G;

        float v[4];
        #pragma unroll
        for (int i = 0; i < 4; ++i) v[i] = sel ? sc[i] : 0.f;

        int idxs[8]; float sigs[8];
        float denom = 0.f, prevv = 0.f;
        #pragma unroll
        for (int r = 0; r < 9; ++r) {
            float bv = v[0]; int bi = 0; float bs = s[0];
            #pragma unroll
            for (int i = 1; i < 4; ++i)
                if (v[i] > bv) { bv = v[i]; bi = i; bs = s[i]; }
            int bidx = (lane << 2) + bi;
            #pragma unroll
            for (int off = 1; off < 64; off <<= 1) {
                float ov = __shfl_xor(bv, off, 64);
                int  oi = __shfl_xor(bidx, off, 64);
                float os = __shfl_xor(bs, off, 64);
                if (ov > bv || (ov == bv && oi < bidx)) { bv = ov; bidx = oi; bs = os; }
            }
            if (r > 0) flag = flag || ((prevv - bv) < EPS_E);
            prevv = bv;
            if (r < 8) {
                idxs[r] = bidx; sigs[r] = bs; denom += bs;
                if ((bidx >> 2) == lane) {
                    #pragma unroll
                    for (int i = 0; i < 4; ++i)
                        if ((bidx & 3) == i) v[i] = -3e38f;
                }
            }
        }
        denom += 1e-20f;
        #pragma unroll
        for (int r = 0; r < 8; ++r)
            if (lane == r) {
                out[n * 8 + r] = (float)idxs[r];
                out[NTOK * 8 + n * 8 + r] = sigs[r] / denom * 2.5f;
            }
        if (flag && lane == 0) {
            int slot = atomicAdd(ws, 1);
            if (slot < cap) ws[16 + slot] = n;
        }
    }
}

// ============ chunked fallback gemm (R8/R14-verified): BM=64 x BN=128 ============
__global__ __launch_bounds__(256, 3)
void gemm3(const float* __restrict__ X, const unsigned short* __restrict__ Whi,
           const unsigned short* __restrict__ Wlo, float* __restrict__ logits,
           int m_base)
{
    __shared__ __align__(16) unsigned short smem[24576];
    unsigned short* Ah = smem;
    unsigned short* Al = smem + 4096;
    unsigned short* Bh = smem + 8192;
    unsigned short* Bl = smem + 16384;

    const int t = threadIdx.x;
    const int lane = t & 63;
    const int w = t >> 6;
    const int wm = w >> 1, wn = w & 1;
    const int fr = lane & 15, fq = lane >> 4;

    const int G = (int)gridDim.x;
    const int swz = (blockIdx.x & 7) * (G >> 3) + (blockIdx.x >> 3);
    const int nb = swz & 1;
    const int mb = swz >> 1;
    const int mloc = mb * 64;
    const int m0 = m_base + mloc;
    const int e0 = nb * 128;

    f32x4 acc[2][4];
    #pragma unroll
    for (int a = 0; a < 2; ++a)
        #pragma unroll
        for (int b = 0; b < 4; ++b) acc[a][b] = (f32x4){0.f, 0.f, 0.f, 0.f};

    const int ar = t >> 2;
    const int akc = t & 3;
    const float* gxa = X + (size_t)(m0 + ar) * H + akc * 16;

    const int blr = lane >> 3;
    const int bsrc = (lane & 7) ^ blr;
    const unsigned short* gbh = Whi + (size_t)(e0 + w * 8 + blr) * H + bsrc * 8;
    const unsigned short* gbl = Wlo + (size_t)(e0 + w * 8 + blr) * H + bsrc * 8;

    float4 xr0, xr1, xr2, xr3;
    auto loadX = [&](int kt) {
        const float* p = gxa + (size_t)kt * 64;
        xr0 = *(const float4*)p;       xr1 = *(const float4*)(p + 4);
        xr2 = *(const float4*)(p + 8); xr3 = *(const float4*)(p + 12);
    };

    loadX(0);

    #pragma unroll 1
    for (int kt = 0; kt < 64; ++kt) {
        __builtin_amdgcn_sched_barrier(0);
        __builtin_amdgcn_s_barrier();
        __builtin_amdgcn_sched_barrier(0);
        const size_t k0 = (size_t)kt * 64;
        #pragma unroll
        for (int i = 0; i < 4; ++i) {
            __builtin_amdgcn_global_load_lds(
                (const __attribute__((address_space(1))) void*)(gbh + (size_t)(32 * i) * H + k0),
                (__attribute__((address_space(3))) void*)&Bh[(w * 8 + 32 * i) * 64], 16, 0, 0);
            __builtin_amdgcn_global_load_lds(
                (const __attribute__((address_space(1))) void*)(gbl + (size_t)(32 * i) * H + k0),
                (__attribute__((address_space(3))) void*)&Bl[(w * 8 + 32 * i) * 64], 16, 0, 0);
        }
        __builtin_amdgcn_sched_barrier(0);
        asm volatile("s_waitcnt vmcnt(8)" ::: "memory");
        __builtin_amdgcn_sched_barrier(0);
        {
            const float xf[16] = {xr0.x, xr0.y, xr0.z, xr0.w, xr1.x, xr1.y, xr1.z, xr1.w,
                                  xr2.x, xr2.y, xr2.z, xr2.w, xr3.x, xr3.y, xr3.z, xr3.w};
            short8 h0, h1, l0, l1;
            #pragma unroll
            for (int j = 0; j < 16; ++j) {
                union { float f; unsigned u; } uu; uu.f = xf[j];
                union { unsigned u; float f; } hh; hh.u = uu.u & 0xFFFF0000u;
                union { float f; unsigned u; } ll; ll.f = xf[j] - hh.f;
                unsigned short hs = (unsigned short)(uu.u >> 16);
                unsigned short ls = (unsigned short)(ll.u >> 16);
                if (j < 8) { h0[j] = (short)hs; l0[j] = (short)ls; }
                else       { h1[j - 8] = (short)hs; l1[j - 8] = (short)ls; }
            }
            const int c0 = akc * 2;
            const int p0 = (c0 ^ (ar & 7)) * 8, p1 = ((c0 + 1) ^ (ar & 7)) * 8;
            *(short8*)&Ah[ar * 64 + p0] = h0;
            *(short8*)&Ah[ar * 64 + p1] = h1;
            *(short8*)&Al[ar * 64 + p0] = l0;
            *(short8*)&Al[ar * 64 + p1] = l1;
        }
        loadX(kt + 1 < 64 ? kt + 1 : 63);
        __builtin_amdgcn_sched_barrier(0);
        asm volatile("s_waitcnt vmcnt(4) lgkmcnt(0)" ::: "memory");
        __builtin_amdgcn_sched_barrier(0);
        __builtin_amdgcn_s_barrier();
        __builtin_amdgcn_sched_barrier(0);
        #pragma unroll
        for (int kk = 0; kk < 2; ++kk) {
            short8 ah[2], al[2], bh[4], bl[4];
            #pragma unroll
            for (int mt = 0; mt < 2; ++mt) {
                const int r = wm * 32 + mt * 16 + fr;
                const int pos = ((kk * 4 + fq) ^ (r & 7)) * 8;
                ah[mt] = *(const short8*)&Ah[r * 64 + pos];
                al[mt] = *(const short8*)&Al[r * 64 + pos];
            }
            #pragma unroll
            for (int nt = 0; nt < 4; ++nt) {
                const int r = wn * 64 + nt * 16 + fr;
                const int pos = ((kk * 4 + fq) ^ (r & 7)) * 8;
                bh[nt] = *(const short8*)&Bh[r * 64 + pos];
                bl[nt] = *(const short8*)&Bl[r * 64 + pos];
            }
            #pragma unroll
            for (int mt = 0; mt < 2; ++mt)
                #pragma unroll
                for (int nt = 0; nt < 4; ++nt)
                    acc[mt][nt] = __builtin_amdgcn_mfma_f32_16x16x32_bf16(ah[mt], bh[nt], acc[mt][nt], 0, 0, 0);
            #pragma unroll
            for (int mt = 0; mt < 2; ++mt)
                #pragma unroll
                for (int nt = 0; nt < 4; ++nt)
                    acc[mt][nt] = __builtin_amdgcn_mfma_f32_16x16x32_bf16(ah[mt], bl[nt], acc[mt][nt], 0, 0, 0);
            #pragma unroll
            for (int mt = 0; mt < 2; ++mt)
                #pragma unroll
                for (int nt = 0; nt < 4; ++nt)
                    acc[mt][nt] = __builtin_amdgcn_mfma_f32_16x16x32_bf16(al[mt], bh[nt], acc[mt][nt], 0, 0, 0);
        }
    }
    asm volatile("" :: "v"(xr0.x), "v"(xr1.x), "v"(xr2.x), "v"(xr3.x));

    #pragma unroll
    for (int mt = 0; mt < 2; ++mt)
        #pragma unroll
        for (int nt = 0; nt < 4; ++nt)
            #pragma unroll
            for (int r = 0; r < 4; ++r)
                logits[(size_t)(mloc + wm * 32 + mt * 16 + fq * 4 + r) * NE +
                       (e0 + wn * 64 + nt * 16 + fr)] = acc[mt][nt][r];
}

// chunked routing (verified)
__global__ __launch_bounds__(256)
void route(const float* __restrict__ logits, const float* __restrict__ bias,
           float* __restrict__ out, int* __restrict__ ws, int cap, int m_base)
{
    const int t = threadIdx.x, lane = t & 63, wv = t >> 6;
    const float4 bf4 = *(const float4*)(bias + lane * 4);
    const float bfa[4] = {bf4.x, bf4.y, bf4.z, bf4.w};

    #pragma unroll 1
    for (int tt = 0; tt < 8; ++tt) {
        const int local = blockIdx.x * 32 + wv * 8 + tt;
        const int n = m_base + local;
        const float4 lg = *(const float4*)&logits[(size_t)local * NE + lane * 4];
        const float lga[4] = {lg.x, lg.y, lg.z, lg.w};
        float s[4], sc[4];
        #pragma unroll
        for (int i = 0; i < 4; ++i) {
            s[i] = 1.f / (1.f + expf(-lga[i]));
            sc[i] = s[i] + bfa[i];
        }
        float a1 = fmaxf(sc[0], sc[1]), a2 = fminf(sc[0], sc[1]);
        float b1 = fmaxf(sc[2], sc[3]), b2 = fminf(sc[2], sc[3]);
        float t1 = fmaxf(a1, b1);
        float t2 = fmaxf(fminf(a1, b1), fmaxf(a2, b2));
        #pragma unroll
        for (int off = 1; off <= 4; off <<= 1) {
            float o1 = __shfl_xor(t1, off, 64);
            float o2 = __shfl_xor(t2, off, 64);
            float n1 = fmaxf(t1, o1);
            float n2 = fmaxf(fminf(t1, o1), fmaxf(t2, o2));
            t1 = n1; t2 = n2;
        }
        const float gsum = t1 + t2;
        float gsv[8];
        #pragma unroll
        for (int g = 0; g < 8; ++g) gsv[g] = __shfl(gsum, g * 8, 64);

        float minsel = 3e38f, maxuns = -3e38f;
        bool sel = false;
        const int myg = lane >> 3;
        #pragma unroll
        for (int g = 0; g < 8; ++g) {
            int cg = 0;
            #pragma unroll
            for (int g2 = 0; g2 < 8; ++g2)
                cg += (gsv[g2] > gsv[g] || (gsv[g2] == gsv[g] && g2 < g)) ? 1 : 0;
            const bool sg = (cg < 4);
            if (sg) minsel = fminf(minsel, gsv[g]); else maxuns = fmaxf(maxuns, gsv[g]);
            if (myg == g) sel = sg;
        }
        bool flag = (minsel - maxuns) < EPS_G;

        float v[4];
        #pragma unroll
        for (int i = 0; i < 4; ++i) v[i] = sel ? sc[i] : 0.f;

        int idxs[8]; float sigs[8];
        float denom = 0.f, prevv = 0.f;
        #pragma unroll
        for (int r = 0; r < 9; ++r) {
            float bv = v[0]; int bi = 0; float bs = s[0];
            #pragma unroll
            for (int i = 1; i < 4; ++i)
                if (v[i] > bv) { bv = v[i]; bi = i; bs = s[i]; }
            int bidx = (lane << 2) + bi;
            #pragma unroll
            for (int off = 1; off < 64; off <<= 1) {
                float ov = __shfl_xor(bv, off, 64);
                int  oi = __shfl_xor(bidx, off, 64);
                float os = __shfl_xor(bs, off, 64);
                if (ov > bv || (ov == bv && oi < bidx)) { bv = ov; bidx = oi; bs = os; }
            }
            if (r > 0) flag = flag || ((prevv - bv) < EPS_E);
            prevv = bv;
            if (r < 8) {
                idxs[r] = bidx; sigs[r] = bs; denom += bs;
                if ((bidx >> 2) == lane) {
                    #pragma unroll
                    for (int i = 0; i < 4; ++i)
                        if ((bidx & 3) == i) v[i] = -3e38f;
                }
            }
        }
        denom += 1e-20f;
        #pragma unroll
        for (int r = 0; r < 8; ++r)
            if (lane == r) {
                out[n * 8 + r] = (float)idxs[r];
                out[NTOK * 8 + n * 8 + r] = sigs[r] / denom * 2.5f;
            }
        if (flag && lane == 0) {
            int slot = atomicAdd(ws, 1);
            if (slot < cap) ws[16 + slot] = n;
        }
    }
}

// ============ fp64 fixup stage A (verified) ============
__global__ __launch_bounds__(256)
void fix1(const float* __restrict__ X, const float* __restrict__ W,
          const int* __restrict__ ws, double* __restrict__ fixlog, int cap)
{
    __shared__ float Xs4[4][4096];
    const int t = threadIdx.x, lane = t & 63, wv = t >> 6;
    int count = ws[0]; if (count > cap) count = cap;
    const int ngrp = (count + 3) >> 2;

    for (int task = blockIdx.x; task < ngrp * 8; task += (int)gridDim.x) {
        const int g = task >> 3, er = task & 7;
        int tok[4];
        #pragma unroll
        for (int q = 0; q < 4; ++q) {
            const int idx = g * 4 + q;
            tok[q] = ws[16 + (idx < count ? idx : g * 4)];
        }
        __syncthreads();
        #pragma unroll
        for (int q = 0; q < 4; ++q)
            for (int k = t * 4; k < 4096; k += 1024)
                *(float4*)&Xs4[q][k] = *(const float4*)(X + (size_t)tok[q] * H + k);
        __syncthreads();
        #pragma unroll 1
        for (int cc = 0; cc < 2; ++cc) {
            const int eb = er * 32 + wv * 8 + cc * 4;
            double a[4][4];
            #pragma unroll
            for (int q = 0; q < 4; ++q)
                #pragma unroll
                for (int ee = 0; ee < 4; ++ee) a[q][ee] = 0.0;
            for (int j = 0; j < 16; ++j) {
                const int kb = (lane + 64 * j) * 4;
                double xx[4][4];
                #pragma unroll
                for (int q = 0; q < 4; ++q) {
                    float4 x4 = *(const float4*)&Xs4[q][kb];
                    xx[q][0] = x4.x; xx[q][1] = x4.y; xx[q][2] = x4.z; xx[q][3] = x4.w;
                }
                #pragma unroll
                for (int ee = 0; ee < 4; ++ee) {
                    float4 w4 = *(const float4*)(W + (size_t)(eb + ee) * H + kb);
                    const double wd[4] = {w4.x, w4.y, w4.z, w4.w};
                    #pragma unroll
                    for (int q = 0; q < 4; ++q)
                        #pragma unroll
                        for (int kq = 0; kq < 4; ++kq)
                            a[q][ee] = fma(xx[q][kq], wd[kq], a[q][ee]);
                }
            }
            #pragma unroll
            for (int q = 0; q < 4; ++q)
                #pragma unroll
                for (int ee = 0; ee < 4; ++ee) {
                    double v = a[q][ee];
                    #pragma unroll
                    for (int off = 1; off < 64; off <<= 1)
                        v += __shfl_xor(v, off, 64);
                    if (lane == 0) fixlog[(size_t)(g * 4 + q) * NE + eb + ee] = v;
                }
        }
    }
}

// ============ fp64 fixup stage B (verified) ============
__global__ __launch_bounds__(256)
void fix2(const double* __restrict__ fixlog, const float* __restrict__ bias,
          float* __restrict__ out, const int* __restrict__ ws, int cap)
{
    const int t = threadIdx.x, lane = t & 63, wv = t >> 6;
    int count = ws[0]; if (count > cap) count = cap;
    const int ngrp = (count + 3) >> 2;

    for (int g = blockIdx.x; g < ngrp; g += (int)gridDim.x) {
        const int idx = g * 4 + wv;
        const int slot = (idx < count) ? idx : g * 4;
        const int n = ws[16 + slot];
        const double* L = fixlog + (size_t)(g * 4 + wv) * NE;

        double s[4], sc[4];
        #pragma unroll
        for (int ii = 0; ii < 4; ++ii) {
            const double Lv = L[lane * 4 + ii];
            s[ii] = 1.0 / (1.0 + exp(-Lv));
            sc[ii] = s[ii] + (double)bias[lane * 4 + ii];
        }
        double a1 = fmax(sc[0], sc[1]), a2 = fmin(sc[0], sc[1]);
        double b1 = fmax(sc[2], sc[3]), b2 = fmin(sc[2], sc[3]);
        double t1 = fmax(a1, b1);
        double t2 = fmax(fmin(a1, b1), fmax(a2, b2));
        #pragma unroll
        for (int off = 1; off <= 4; off <<= 1) {
            double o1 = __shfl_xor(t1, off, 64);
            double o2 = __shfl_xor(t2, off, 64);
            double n1 = fmax(t1, o1);
            double n2 = fmax(fmin(t1, o1), fmax(t2, o2));
            t1 = n1; t2 = n2;
        }
        const double gsum = t1 + t2;
        double gsv[8];
        #pragma unroll
        for (int gg = 0; gg < 8; ++gg) gsv[gg] = __shfl(gsum, gg * 8, 64);
        const int myg = lane >> 3;
        int cnt = 0;
        #pragma unroll
        for (int gg = 0; gg < 8; ++gg)
            cnt += (gsv[gg] > gsum || (gsv[gg] == gsum && gg < myg)) ? 1 : 0;
        const bool sel = (cnt < 4);

        double v[4];
        #pragma unroll
        for (int ii = 0; ii < 4; ++ii) v[ii] = sel ? sc[ii] : 0.0;

        int idxs[8]; double sigs[8];
        double denom = 0.0;
        #pragma unroll
        for (int r = 0; r < 8; ++r) {
            double bv = v[0]; int bi = 0; double bs = s[0];
            #pragma unroll
            for (int ii = 1; ii < 4; ++ii)
                if (v[ii] > bv) { bv = v[ii]; bi = ii; bs = s[ii]; }
            int bidx = (lane << 2) + bi;
            #pragma unroll
            for (int off = 1; off < 64; off <<= 1) {
                double ov = __shfl_xor(bv, off, 64);
                int oi = __shfl_xor(bidx, off, 64);
                double os = __shfl_xor(bs, off, 64);
                if (ov > bv || (ov == bv && oi < bidx)) { bv = ov; bidx = oi; bs = os; }
            }
            idxs[r] = bidx; sigs[r] = bs; denom += bs;
            if ((bidx >> 2) == lane) {
                #pragma unroll
                for (int ii = 0; ii < 4; ++ii)
                    if ((bidx & 3) == ii) v[ii] = -1.0e300;
            }
        }
        denom += 1e-20;
        #pragma unroll
        for (int r = 0; r < 8; ++r)
            if (lane == r) {
                out[n * 8 + r] = (float)idxs[r];
                out[NTOK * 8 + n * 8 + r] = (float)(sigs[r] / denom * 2.5);
            }
    }
}

// low fallback: exact fp64 (slow but correct)
#define FXP 34
#define FEP 260
__global__ __launch_bounds__(256)
void moe_fb(const float* __restrict__ X, const float* __restrict__ W,
            const float* __restrict__ bias, float* __restrict__ out)
{
    __shared__ double Xs[16 * FXP];
    __shared__ double Ws[16 * FEP];
    const int t = threadIdx.x;
    const int lane = t & 63;
    const int wv = t >> 6;
    const int m0 = blockIdx.x * 32;
    double acc[8][4];
    #pragma unroll
    for (int i = 0; i < 8; ++i)
        #pragma unroll
        for (int j = 0; j < 4; ++j) acc[i][j] = 0.0;
    const int xm = t >> 3, xk = (t & 7) * 2;
    const int we = t >> 2, wk = (t & 3) * 4;
    const float* gx = X + (size_t)(m0 + xm) * H + xk;
    const float* gw = W + (size_t)we * H + wk;
    float2 xreg = *(const float2*)(gx);
    float4 wreg[4];
    #pragma unroll
    for (int p = 0; p < 4; ++p) wreg[p] = *(const float4*)(gw + (size_t)(64 * p) * H);
    const int NT = H / 16;
    for (int t0 = 0; t0 < NT; ++t0) {
        __syncthreads();
        Xs[(xk + 0) * FXP + xm] = (double)xreg.x;
        Xs[(xk + 1) * FXP + xm] = (double)xreg.y;
        #pragma unroll
        for (int p = 0; p < 4; ++p) {
            const int e = we + 64 * p;
            Ws[(wk + 0) * FEP + e] = (double)wreg[p].x;
            Ws[(wk + 1) * FEP + e] = (double)wreg[p].y;
            Ws[(wk + 2) * FEP + e] = (double)wreg[p].z;
            Ws[(wk + 3) * FEP + e] = (double)wreg[p].w;
        }
        __syncthreads();
        if (t0 + 1 < NT) {
            const int off = (t0 + 1) * 16;
            xreg = *(const float2*)(gx + off);
            #pragma unroll
            for (int p = 0; p < 4; ++p) wreg[p] = *(const float4*)(gw + (size_t)(64 * p) * H + off);
        }
        #pragma unroll
        for (int j = 0; j < 16; ++j) {
            const double* xrow = &Xs[j * FXP + wv * 8];
            const double2 wa = *(const double2*)&Ws[j * FEP + lane * 4];
            const double2 wb = *(const double2*)&Ws[j * FEP + lane * 4 + 2];
            const double ws4[4] = {wa.x, wa.y, wb.x, wb.y};
            #pragma unroll
            for (int mi = 0; mi < 8; ++mi)
                #pragma unroll
                for (int ei = 0; ei < 4; ++ei)
                    acc[mi][ei] = fma(xrow[mi], ws4[ei], acc[mi][ei]);
        }
    }
    const float4 bf = *(const float4*)(bias + lane * 4);
    const double bfa[4] = {(double)bf.x, (double)bf.y, (double)bf.z, (double)bf.w};
    #pragma unroll 1
    for (int tt = 0; tt < 8; ++tt) {
        double s[4], sc[4];
        #pragma unroll
        for (int i = 0; i < 4; ++i) {
            s[i] = 1.0 / (1.0 + exp(-acc[tt][i]));
            sc[i] = s[i] + bfa[i];
        }
        double a1 = fmax(sc[0], sc[1]), a2 = fmin(sc[0], sc[1]);
        double b1 = fmax(sc[2], sc[3]), b2 = fmin(sc[2], sc[3]);
        double t1 = fmax(a1, b1);
        double t2 = fmax(fmin(a1, b1), fmax(a2, b2));
        #pragma unroll
        for (int off = 1; off <= 4; off <<= 1) {
            double o1 = __shfl_xor(t1, off, 64);
            double o2 = __shfl_xor(t2, off, 64);
            double n1 = fmax(t1, o1);
            double n2 = fmax(fmin(t1, o1), fmax(t2, o2));
            t1 = n1; t2 = n2;
        }
        const double gsum = t1 + t2;
        double gsv[8];
        #pragma unroll
        for (int g = 0; g < 8; ++g) gsv[g] = __shfl(gsum, g * 8, 64);
        const int myg = lane >> 3;
        int cnt = 0;
        #pragma unroll
        for (int g = 0; g < 8; ++g)
            cnt += (gsv[g] > gsum || (gsv[g] == gsum && g < myg)) ? 1 : 0;
        const bool sel = (cnt < 4);
        double v[4];
        #pragma unroll
        for (int i = 0; i < 4; ++i) v[i] = sel ? sc[i] : 0.0;
        int idxs[8]; double sigs[8];
        double denom = 0.0;
        #pragma unroll
        for (int r = 0; r < 8; ++r) {
            double bv = v[0]; int bi = 0; double bs = s[0];
            #pragma unroll
            for (int i = 1; i < 4; ++i)
                if (v[i] > bv) { bv = v[i]; bi = i; bs = s[i]; }
            int bidx = (lane << 2) + bi;
            #pragma unroll
            for (int off = 1; off < 64; off <<= 1) {
                double ov = __shfl_xor(bv, off, 64);
                int oi = __shfl_xor(bidx, off, 64);
                double os = __shfl_xor(bs, off, 64);
                if (ov > bv || (ov == bv && oi < bidx)) { bv = ov; bidx = oi; bs = os; }
            }
            idxs[r] = bidx; sigs[r] = bs; denom += bs;
            if ((bidx >> 2) == lane) {
                #pragma unroll
                for (int i = 0; i < 4; ++i)
                    if ((bidx & 3) == i) v[i] = -1.0e300;
            }
        }
        denom += 1e-20;
        const size_t n = (size_t)(m0 + wv * 8 + tt);
        #pragma unroll
        for (int r = 0; r < 8; ++r)
            if (lane == r) {
                out[n * 8 + r] = (float)idxs[r];
                out[(size_t)NTOK * 8 + n * 8 + r] = (float)(sigs[r] / denom * 2.5);
            }
    }
}

extern "C" void kernel_launch(void* const* d_in, const int* in_sizes, int n_in,
                              void* d_out, int out_size, void* d_ws, size_t ws_size,
                              hipStream_t stream) {
    const float* X = (const float*)d_in[0];
    const float* W = (const float*)d_in[1];
    const float* bias = (const float*)d_in[2];
    float* out = (float*)d_out;

    const size_t WB = (size_t)NE * H * 2;
    const size_t OFF_W = 65536;
    const size_t OFF_FIX = OFF_W + 2 * WB;
    const size_t FIXB = (size_t)FIXCAP * NE * 8;
    const size_t OFF_LOG = OFF_FIX + FIXB;
    const size_t minlog = (size_t)256 * NE * 4;
    const size_t full = (size_t)NTOK * NE * 4;

    if (ws_size < OFF_LOG + minlog) {
        moe_fb<<<NTOK / 32, 256, 0, stream>>>(X, W, bias, out);
        return;
    }
    int* ws = (int*)d_ws;
    unsigned short* whi = (unsigned short*)((char*)d_ws + OFF_W);
    unsigned short* wlo = whi + (size_t)NE * H;
    double* fixlog = (double*)((char*)d_ws + OFF_FIX);
    float* logits = (float*)((char*)d_ws + OFF_LOG);
    const size_t avail = ws_size - OFF_LOG;

    split_w<<<(NE * H) / 1024, 256, 0, stream>>>(W, whi, wlo, ws);

    if (avail >= 2 * full) {
        // split-K path: BM=BN=128, two half-K logits buffers
        float* l0 = logits;
        float* l1 = logits + (size_t)NTOK * NE;
        gemm3sk<<<512, 256, 0, stream>>>(X, whi, wlo, l0, l1);
        route2<<<NTOK / 32, 256, 0, stream>>>(l0, l1, bias, out, ws, FLAGCAP);
    } else {
        int CT;
        if (avail >= full) CT = NTOK;
        else {
            CT = (int)(avail / ((size_t)NE * 4));
            CT &= ~255;
        }
        for (int mb0 = 0; mb0 < NTOK; mb0 += CT) {
            int ct = (NTOK - mb0 < CT) ? (NTOK - mb0) : CT;
            gemm3<<<(ct / 64) * 2, 256, 0, stream>>>(X, whi, wlo, logits, mb0);
            route<<<ct / 32, 256, 0, stream>>>(logits, bias, out, ws, FLAGCAP, mb0);
        }
    }
    fix1<<<1024, 256, 0, stream>>>(X, W, ws, fixlog, FIXCAP);
    fix2<<<256, 256, 0, stream>>>(fixlog, bias, out, ws, FIXCAP);
}

// Round 16
// 221.767 us; speedup vs baseline: 1.0306x; 1.0306x over previous
//
#include <hip/hip_runtime.h>
#include <math.h>

#define NTOK 16384
#define H 4096
#define NE 256
#define EPS_E 1.2e-5f
#define EPS_G 2.4e-5f
#define FIXCAP 1024
#define FLAGCAP 8192

typedef __attribute__((ext_vector_type(8))) short short8;
typedef __attribute__((ext_vector_type(4))) float f32x4;

__device__ __forceinline__ unsigned short f2bf(float x) {
    union { float f; unsigned u; } v; v.f = x;
    unsigned r = v.u + 0x7FFF + ((v.u >> 16) & 1);
    return (unsigned short)(r >> 16);
}
__device__ __forceinline__ float bf2f(unsigned short h) {
    union { float f; unsigned u; } v; v.u = ((unsigned)h) << 16;
    return v.f;
}

__global__ __launch_bounds__(256)
void split_w(const float* __restrict__ W, unsigned short* __restrict__ whi,
             unsigned short* __restrict__ wlo, int* __restrict__ ws)
{
    if (blockIdx.x == 0 && threadIdx.x == 0) ws[0] = 0;
    const int i = (blockIdx.x * 256 + threadIdx.x) * 4;
    float4 w4 = *(const float4*)(W + i);
    const float wv[4] = {w4.x, w4.y, w4.z, w4.w};
    ushort4 hh, ll;
    unsigned short* hp = (unsigned short*)&hh;
    unsigned short* lp = (unsigned short*)&ll;
    #pragma unroll
    for (int j = 0; j < 4; ++j) {
        unsigned short h = f2bf(wv[j]);
        hp[j] = h;
        lp[j] = f2bf(wv[j] - bf2f(h));
    }
    *(ushort4*)(whi + i) = hh;
    *(ushort4*)(wlo + i) = ll;
}

// ============ Stage 1 (R8-verified config): BM=64 x BN=128, 48KB, 3 blocks/CU ============
__global__ __launch_bounds__(256, 3)
void gemm3(const float* __restrict__ X, const unsigned short* __restrict__ Whi,
           const unsigned short* __restrict__ Wlo, float* __restrict__ logits,
           int m_base)
{
    __shared__ __align__(16) unsigned short smem[24576];  // 48 KB
    unsigned short* Ah = smem;              // [64][64] bf16 swizzled
    unsigned short* Al = smem + 4096;
    unsigned short* Bh = smem + 8192;       // [128][64]
    unsigned short* Bl = smem + 16384;

    const int t = threadIdx.x;
    const int lane = t & 63;
    const int w = t >> 6;                   // 0..3
    const int wm = w >> 1, wn = w & 1;
    const int fr = lane & 15, fq = lane >> 4;

    const int G = (int)gridDim.x;
    const int swz = (blockIdx.x & 7) * (G >> 3) + (blockIdx.x >> 3);
    const int nb = swz & 1;
    const int mb = swz >> 1;
    const int mloc = mb * 64;
    const int m0 = m_base + mloc;
    const int e0 = nb * 128;

    f32x4 acc[2][4];
    #pragma unroll
    for (int a = 0; a < 2; ++a)
        #pragma unroll
        for (int b = 0; b < 4; ++b) acc[a][b] = (f32x4){0.f, 0.f, 0.f, 0.f};

    // A staging: thread t -> row ar (0..63), 16 contiguous floats at chunk akc
    const int ar = t >> 2;
    const int akc = t & 3;
    const float* gxa = X + (size_t)(m0 + ar) * H + akc * 16;

    // B staging via global_load_lds (linear dest, pre-swizzled source)
    const int blr = lane >> 3;
    const int bsrc = (lane & 7) ^ blr;
    const unsigned short* gbh = Whi + (size_t)(e0 + w * 8 + blr) * H + bsrc * 8;
    const unsigned short* gbl = Wlo + (size_t)(e0 + w * 8 + blr) * H + bsrc * 8;

    float4 xr0, xr1, xr2, xr3;
    auto loadX = [&](int kt) {
        const float* p = gxa + (size_t)kt * 64;
        xr0 = *(const float4*)p;       xr1 = *(const float4*)(p + 4);
        xr2 = *(const float4*)(p + 8); xr3 = *(const float4*)(p + 12);
    };

    loadX(0);   // X(0) in flight: 4 loads

    #pragma unroll 1
    for (int kt = 0; kt < 64; ++kt) {
        // all waves done reading previous tile
        __builtin_amdgcn_sched_barrier(0);
        __builtin_amdgcn_s_barrier();
        __builtin_amdgcn_sched_barrier(0);
        // issue B(kt): 8 gload_lds (in-flight: X 4 old + B 8 new)
        const size_t k0 = (size_t)kt * 64;
        #pragma unroll
        for (int i = 0; i < 4; ++i) {
            __builtin_amdgcn_global_load_lds(
                (const __attribute__((address_space(1))) void*)(gbh + (size_t)(32 * i) * H + k0),
                (__attribute__((address_space(3))) void*)&Bh[(w * 8 + 32 * i) * 64], 16, 0, 0);
            __builtin_amdgcn_global_load_lds(
                (const __attribute__((address_space(1))) void*)(gbl + (size_t)(32 * i) * H + k0),
                (__attribute__((address_space(3))) void*)&Bl[(w * 8 + 32 * i) * 64], 16, 0, 0);
        }
        __builtin_amdgcn_sched_barrier(0);
        // X(kt) regs ready (drain the 4 oldest; B stays in flight)
        asm volatile("s_waitcnt vmcnt(8)" ::: "memory");
        __builtin_amdgcn_sched_barrier(0);
        // split X(kt) (truncation split) -> swizzled A LDS writes
        {
            const float xf[16] = {xr0.x, xr0.y, xr0.z, xr0.w, xr1.x, xr1.y, xr1.z, xr1.w,
                                  xr2.x, xr2.y, xr2.z, xr2.w, xr3.x, xr3.y, xr3.z, xr3.w};
            short8 h0, h1, l0, l1;
            #pragma unroll
            for (int j = 0; j < 16; ++j) {
                union { float f; unsigned u; } uu; uu.f = xf[j];
                union { unsigned u; float f; } hh; hh.u = uu.u & 0xFFFF0000u;
                union { float f; unsigned u; } ll; ll.f = xf[j] - hh.f;
                unsigned short hs = (unsigned short)(uu.u >> 16);
                unsigned short ls = (unsigned short)(ll.u >> 16);
                if (j < 8) { h0[j] = (short)hs; l0[j] = (short)ls; }
                else       { h1[j - 8] = (short)hs; l1[j - 8] = (short)ls; }
            }
            const int c0 = akc * 2;
            const int p0 = (c0 ^ (ar & 7)) * 8, p1 = ((c0 + 1) ^ (ar & 7)) * 8;
            *(short8*)&Ah[ar * 64 + p0] = h0;
            *(short8*)&Ah[ar * 64 + p1] = h1;
            *(short8*)&Al[ar * 64 + p0] = l0;
            *(short8*)&Al[ar * 64 + p1] = l1;
        }
        // prefetch X(kt+1) (kept in flight across the barrier)
        loadX(kt + 1 < 64 ? kt + 1 : 63);
        __builtin_amdgcn_sched_barrier(0);
        // B(kt) landed + A writes visible; X(kt+1) stays in flight
        asm volatile("s_waitcnt vmcnt(4) lgkmcnt(0)" ::: "memory");
        __builtin_amdgcn_sched_barrier(0);
        __builtin_amdgcn_s_barrier();
        __builtin_amdgcn_sched_barrier(0);
        // compute: 48 MFMAs/wave
        #pragma unroll
        for (int kk = 0; kk < 2; ++kk) {
            short8 ah[2], al[2], bh[4], bl[4];
            #pragma unroll
            for (int mt = 0; mt < 2; ++mt) {
                const int r = wm * 32 + mt * 16 + fr;
                const int pos = ((kk * 4 + fq) ^ (r & 7)) * 8;
                ah[mt] = *(const short8*)&Ah[r * 64 + pos];
                al[mt] = *(const short8*)&Al[r * 64 + pos];
            }
            #pragma unroll
            for (int nt = 0; nt < 4; ++nt) {
                const int r = wn * 64 + nt * 16 + fr;
                const int pos = ((kk * 4 + fq) ^ (r & 7)) * 8;
                bh[nt] = *(const short8*)&Bh[r * 64 + pos];
                bl[nt] = *(const short8*)&Bl[r * 64 + pos];
            }
            #pragma unroll
            for (int mt = 0; mt < 2; ++mt)
                #pragma unroll
                for (int nt = 0; nt < 4; ++nt)
                    acc[mt][nt] = __builtin_amdgcn_mfma_f32_16x16x32_bf16(ah[mt], bh[nt], acc[mt][nt], 0, 0, 0);
            #pragma unroll
            for (int mt = 0; mt < 2; ++mt)
                #pragma unroll
                for (int nt = 0; nt < 4; ++nt)
                    acc[mt][nt] = __builtin_amdgcn_mfma_f32_16x16x32_bf16(ah[mt], bl[nt], acc[mt][nt], 0, 0, 0);
            #pragma unroll
            for (int mt = 0; mt < 2; ++mt)
                #pragma unroll
                for (int nt = 0; nt < 4; ++nt)
                    acc[mt][nt] = __builtin_amdgcn_mfma_f32_16x16x32_bf16(al[mt], bh[nt], acc[mt][nt], 0, 0, 0);
        }
    }
    // keep tail X prefetch alive so per-iter vmcnt counts stay exact
    asm volatile("" :: "v"(xr0.x), "v"(xr1.x), "v"(xr2.x), "v"(xr3.x));

    // store logits (local token index)
    #pragma unroll
    for (int mt = 0; mt < 2; ++mt)
        #pragma unroll
        for (int nt = 0; nt < 4; ++nt)
            #pragma unroll
            for (int r = 0; r < 4; ++r)
                logits[(size_t)(mloc + wm * 32 + mt * 16 + fq * 4 + r) * NE +
                       (e0 + wn * 64 + nt * 16 + fr)] = acc[mt][nt][r];
}

// ============ Stage 2: routing from fp32 logits (verified epilogue) ============
__global__ __launch_bounds__(256)
void route(const float* __restrict__ logits, const float* __restrict__ bias,
           float* __restrict__ out, int* __restrict__ ws, int cap, int m_base)
{
    const int t = threadIdx.x, lane = t & 63, wv = t >> 6;
    const float4 bf4 = *(const float4*)(bias + lane * 4);
    const float bfa[4] = {bf4.x, bf4.y, bf4.z, bf4.w};

    #pragma unroll 1
    for (int tt = 0; tt < 8; ++tt) {
        const int local = blockIdx.x * 32 + wv * 8 + tt;
        const int n = m_base + local;
        const float4 lg = *(const float4*)&logits[(size_t)local * NE + lane * 4];
        const float lga[4] = {lg.x, lg.y, lg.z, lg.w};
        float s[4], sc[4];
        #pragma unroll
        for (int i = 0; i < 4; ++i) {
            s[i] = 1.f / (1.f + expf(-lga[i]));
            sc[i] = s[i] + bfa[i];
        }
        float a1 = fmaxf(sc[0], sc[1]), a2 = fminf(sc[0], sc[1]);
        float b1 = fmaxf(sc[2], sc[3]), b2 = fminf(sc[2], sc[3]);
        float t1 = fmaxf(a1, b1);
        float t2 = fmaxf(fminf(a1, b1), fmaxf(a2, b2));
        #pragma unroll
        for (int off = 1; off <= 4; off <<= 1) {
            float o1 = __shfl_xor(t1, off, 64);
            float o2 = __shfl_xor(t2, off, 64);
            float n1 = fmaxf(t1, o1);
            float n2 = fmaxf(fminf(t1, o1), fmaxf(t2, o2));
            t1 = n1; t2 = n2;
        }
        const float gsum = t1 + t2;
        float gsv[8];
        #pragma unroll
        for (int g = 0; g < 8; ++g) gsv[g] = __shfl(gsum, g * 8, 64);

        float minsel = 3e38f, maxuns = -3e38f;
        bool sel = false;
        const int myg = lane >> 3;
        #pragma unroll
        for (int g = 0; g < 8; ++g) {
            int cg = 0;
            #pragma unroll
            for (int g2 = 0; g2 < 8; ++g2)
                cg += (gsv[g2] > gsv[g] || (gsv[g2] == gsv[g] && g2 < g)) ? 1 : 0;
            const bool sg = (cg < 4);
            if (sg) minsel = fminf(minsel, gsv[g]); else maxuns = fmaxf(maxuns, gsv[g]);
            if (myg == g) sel = sg;
        }
        bool flag = (minsel - maxuns) < EPS_G;

        float v[4];
        #pragma unroll
        for (int i = 0; i < 4; ++i) v[i] = sel ? sc[i] : 0.f;

        int idxs[8]; float sigs[8];
        float denom = 0.f, prevv = 0.f;
        #pragma unroll
        for (int r = 0; r < 9; ++r) {
            float bv = v[0]; int bi = 0; float bs = s[0];
            #pragma unroll
            for (int i = 1; i < 4; ++i)
                if (v[i] > bv) { bv = v[i]; bi = i; bs = s[i]; }
            int bidx = (lane << 2) + bi;
            #pragma unroll
            for (int off = 1; off < 64; off <<= 1) {
                float ov = __shfl_xor(bv, off, 64);
                int  oi = __shfl_xor(bidx, off, 64);
                float os = __shfl_xor(bs, off, 64);
                if (ov > bv || (ov == bv && oi < bidx)) { bv = ov; bidx = oi; bs = os; }
            }
            if (r > 0) flag = flag || ((prevv - bv) < EPS_E);
            prevv = bv;
            if (r < 8) {
                idxs[r] = bidx; sigs[r] = bs; denom += bs;
                if ((bidx >> 2) == lane) {
                    #pragma unroll
                    for (int i = 0; i < 4; ++i)
                        if ((bidx & 3) == i) v[i] = -3e38f;
                }
            }
        }
        denom += 1e-20f;
        #pragma unroll
        for (int r = 0; r < 8; ++r)
            if (lane == r) {
                out[n * 8 + r] = (float)idxs[r];
                out[NTOK * 8 + n * 8 + r] = sigs[r] / denom * 2.5f;
            }
        if (flag && lane == 0) {
            int slot = atomicAdd(ws, 1);
            if (slot < cap) ws[16 + slot] = n;
        }
    }
}

// ============ fp64 fixup stage A: exact logits, expert-parallel ============
__global__ __launch_bounds__(256)
void fix1(const float* __restrict__ X, const float* __restrict__ W,
          const int* __restrict__ ws, double* __restrict__ fixlog, int cap)
{
    __shared__ float Xs4[4][4096];
    const int t = threadIdx.x, lane = t & 63, wv = t >> 6;
    int count = ws[0]; if (count > cap) count = cap;
    const int ngrp = (count + 3) >> 2;

    for (int task = blockIdx.x; task < ngrp * 8; task += (int)gridDim.x) {
        const int g = task >> 3, er = task & 7;
        int tok[4];
        #pragma unroll
        for (int q = 0; q < 4; ++q) {
            const int idx = g * 4 + q;
            tok[q] = ws[16 + (idx < count ? idx : g * 4)];
        }
        __syncthreads();
        #pragma unroll
        for (int q = 0; q < 4; ++q)
            for (int k = t * 4; k < 4096; k += 1024)
                *(float4*)&Xs4[q][k] = *(const float4*)(X + (size_t)tok[q] * H + k);
        __syncthreads();
        #pragma unroll 1
        for (int cc = 0; cc < 2; ++cc) {
            const int eb = er * 32 + wv * 8 + cc * 4;
            double a[4][4];
            #pragma unroll
            for (int q = 0; q < 4; ++q)
                #pragma unroll
                for (int ee = 0; ee < 4; ++ee) a[q][ee] = 0.0;
            for (int j = 0; j < 16; ++j) {
                const int kb = (lane + 64 * j) * 4;
                double xx[4][4];
                #pragma unroll
                for (int q = 0; q < 4; ++q) {
                    float4 x4 = *(const float4*)&Xs4[q][kb];
                    xx[q][0] = x4.x; xx[q][1] = x4.y; xx[q][2] = x4.z; xx[q][3] = x4.w;
                }
                #pragma unroll
                for (int ee = 0; ee < 4; ++ee) {
                    float4 w4 = *(const float4*)(W + (size_t)(eb + ee) * H + kb);
                    const double wd[4] = {w4.x, w4.y, w4.z, w4.w};
                    #pragma unroll
                    for (int q = 0; q < 4; ++q)
                        #pragma unroll
                        for (int kq = 0; kq < 4; ++kq)
                            a[q][ee] = fma(xx[q][kq], wd[kq], a[q][ee]);
                }
            }
            #pragma unroll
            for (int q = 0; q < 4; ++q)
                #pragma unroll
                for (int ee = 0; ee < 4; ++ee) {
                    double v = a[q][ee];
                    #pragma unroll
                    for (int off = 1; off < 64; off <<= 1)
                        v += __shfl_xor(v, off, 64);
                    if (lane == 0) fixlog[(size_t)(g * 4 + q) * NE + eb + ee] = v;
                }
        }
    }
}

// ============ fp64 fixup stage B: routing from exact logits ============
__global__ __launch_bounds__(256)
void fix2(const double* __restrict__ fixlog, const float* __restrict__ bias,
          float* __restrict__ out, const int* __restrict__ ws, int cap)
{
    const int t = threadIdx.x, lane = t & 63, wv = t >> 6;
    int count = ws[0]; if (count > cap) count = cap;
    const int ngrp = (count + 3) >> 2;

    for (int g = blockIdx.x; g < ngrp; g += (int)gridDim.x) {
        const int idx = g * 4 + wv;
        const int slot = (idx < count) ? idx : g * 4;
        const int n = ws[16 + slot];
        const double* L = fixlog + (size_t)(g * 4 + wv) * NE;

        double s[4], sc[4];
        #pragma unroll
        for (int ii = 0; ii < 4; ++ii) {
            const double Lv = L[lane * 4 + ii];
            s[ii] = 1.0 / (1.0 + exp(-Lv));
            sc[ii] = s[ii] + (double)bias[lane * 4 + ii];
        }
        double a1 = fmax(sc[0], sc[1]), a2 = fmin(sc[0], sc[1]);
        double b1 = fmax(sc[2], sc[3]), b2 = fmin(sc[2], sc[3]);
        double t1 = fmax(a1, b1);
        double t2 = fmax(fmin(a1, b1), fmax(a2, b2));
        #pragma unroll
        for (int off = 1; off <= 4; off <<= 1) {
            double o1 = __shfl_xor(t1, off, 64);
            double o2 = __shfl_xor(t2, off, 64);
            double n1 = fmax(t1, o1);
            double n2 = fmax(fmin(t1, o1), fmax(t2, o2));
            t1 = n1; t2 = n2;
        }
        const double gsum = t1 + t2;
        double gsv[8];
        #pragma unroll
        for (int gg = 0; gg < 8; ++gg) gsv[gg] = __shfl(gsum, gg * 8, 64);
        const int myg = lane >> 3;
        int cnt = 0;
        #pragma unroll
        for (int gg = 0; gg < 8; ++gg)
            cnt += (gsv[gg] > gsum || (gsv[gg] == gsum && gg < myg)) ? 1 : 0;
        const bool sel = (cnt < 4);

        double v[4];
        #pragma unroll
        for (int ii = 0; ii < 4; ++ii) v[ii] = sel ? sc[ii] : 0.0;

        int idxs[8]; double sigs[8];
        double denom = 0.0;
        #pragma unroll
        for (int r = 0; r < 8; ++r) {
            double bv = v[0]; int bi = 0; double bs = s[0];
            #pragma unroll
            for (int ii = 1; ii < 4; ++ii)
                if (v[ii] > bv) { bv = v[ii]; bi = ii; bs = s[ii]; }
            int bidx = (lane << 2) + bi;
            #pragma unroll
            for (int off = 1; off < 64; off <<= 1) {
                double ov = __shfl_xor(bv, off, 64);
                int oi = __shfl_xor(bidx, off, 64);
                double os = __shfl_xor(bs, off, 64);
                if (ov > bv || (ov == bv && oi < bidx)) { bv = ov; bidx = oi; bs = os; }
            }
            idxs[r] = bidx; sigs[r] = bs; denom += bs;
            if ((bidx >> 2) == lane) {
                #pragma unroll
                for (int ii = 0; ii < 4; ++ii)
                    if ((bidx & 3) == ii) v[ii] = -1.0e300;
            }
        }
        denom += 1e-20;
        #pragma unroll
        for (int r = 0; r < 8; ++r)
            if (lane == r) {
                out[n * 8 + r] = (float)idxs[r];
                out[NTOK * 8 + n * 8 + r] = (float)(sigs[r] / denom * 2.5);
            }
    }
}

// low fallback: exact fp64 (slow but correct)
#define FXP 34
#define FEP 260
__global__ __launch_bounds__(256)
void moe_fb(const float* __restrict__ X, const float* __restrict__ W,
            const float* __restrict__ bias, float* __restrict__ out)
{
    __shared__ double Xs[16 * FXP];
    __shared__ double Ws[16 * FEP];
    const int t = threadIdx.x;
    const int lane = t & 63;
    const int wv = t >> 6;
    const int m0 = blockIdx.x * 32;
    double acc[8][4];
    #pragma unroll
    for (int i = 0; i < 8; ++i)
        #pragma unroll
        for (int j = 0; j < 4; ++j) acc[i][j] = 0.0;
    const int xm = t >> 3, xk = (t & 7) * 2;
    const int we = t >> 2, wk = (t & 3) * 4;
    const float* gx = X + (size_t)(m0 + xm) * H + xk;
    const float* gw = W + (size_t)we * H + wk;
    float2 xreg = *(const float2*)(gx);
    float4 wreg[4];
    #pragma unroll
    for (int p = 0; p < 4; ++p) wreg[p] = *(const float4*)(gw + (size_t)(64 * p) * H);
    const int NT = H / 16;
    for (int t0 = 0; t0 < NT; ++t0) {
        __syncthreads();
        Xs[(xk + 0) * FXP + xm] = (double)xreg.x;
        Xs[(xk + 1) * FXP + xm] = (double)xreg.y;
        #pragma unroll
        for (int p = 0; p < 4; ++p) {
            const int e = we + 64 * p;
            Ws[(wk + 0) * FEP + e] = (double)wreg[p].x;
            Ws[(wk + 1) * FEP + e] = (double)wreg[p].y;
            Ws[(wk + 2) * FEP + e] = (double)wreg[p].z;
            Ws[(wk + 3) * FEP + e] = (double)wreg[p].w;
        }
        __syncthreads();
        if (t0 + 1 < NT) {
            const int off = (t0 + 1) * 16;
            xreg = *(const float2*)(gx + off);
            #pragma unroll
            for (int p = 0; p < 4; ++p) wreg[p] = *(const float4*)(gw + (size_t)(64 * p) * H + off);
        }
        #pragma unroll
        for (int j = 0; j < 16; ++j) {
            const double* xrow = &Xs[j * FXP + wv * 8];
            const double2 wa = *(const double2*)&Ws[j * FEP + lane * 4];
            const double2 wb = *(const double2*)&Ws[j * FEP + lane * 4 + 2];
            const double ws4[4] = {wa.x, wa.y, wb.x, wb.y};
            #pragma unroll
            for (int mi = 0; mi < 8; ++mi)
                #pragma unroll
                for (int ei = 0; ei < 4; ++ei)
                    acc[mi][ei] = fma(xrow[mi], ws4[ei], acc[mi][ei]);
        }
    }
    const float4 bf = *(const float4*)(bias + lane * 4);
    const double bfa[4] = {(double)bf.x, (double)bf.y, (double)bf.z, (double)bf.w};
    #pragma unroll 1
    for (int tt = 0; tt < 8; ++tt) {
        double s[4], sc[4];
        #pragma unroll
        for (int i = 0; i < 4; ++i) {
            s[i] = 1.0 / (1.0 + exp(-acc[tt][i]));
            sc[i] = s[i] + bfa[i];
        }
        double a1 = fmax(sc[0], sc[1]), a2 = fmin(sc[0], sc[1]);
        double b1 = fmax(sc[2], sc[3]), b2 = fmin(sc[2], sc[3]);
        double t1 = fmax(a1, b1);
        double t2 = fmax(fmin(a1, b1), fmax(a2, b2));
        #pragma unroll
        for (int off = 1; off <= 4; off <<= 1) {
            double o1 = __shfl_xor(t1, off, 64);
            double o2 = __shfl_xor(t2, off, 64);
            double n1 = fmax(t1, o1);
            double n2 = fmax(fmin(t1, o1), fmax(t2, o2));
            t1 = n1; t2 = n2;
        }
        const double gsum = t1 + t2;
        double gsv[8];
        #pragma unroll
        for (int g = 0; g < 8; ++g) gsv[g] = __shfl(gsum, g * 8, 64);
        const int myg = lane >> 3;
        int cnt = 0;
        #pragma unroll
        for (int g = 0; g < 8; ++g)
            cnt += (gsv[g] > gsum || (gsv[g] == gsum && g < myg)) ? 1 : 0;
        const bool sel = (cnt < 4);
        double v[4];
        #pragma unroll
        for (int i = 0; i < 4; ++i) v[i] = sel ? sc[i] : 0.0;
        int idxs[8]; double sigs[8];
        double denom = 0.0;
        #pragma unroll
        for (int r = 0; r < 8; ++r) {
            double bv = v[0]; int bi = 0; double bs = s[0];
            #pragma unroll
            for (int i = 1; i < 4; ++i)
                if (v[i] > bv) { bv = v[i]; bi = i; bs = s[i]; }
            int bidx = (lane << 2) + bi;
            #pragma unroll
            for (int off = 1; off < 64; off <<= 1) {
                double ov = __shfl_xor(bv, off, 64);
                int oi = __shfl_xor(bidx, off, 64);
                double os = __shfl_xor(bs, off, 64);
                if (ov > bv || (ov == bv && oi < bidx)) { bv = ov; bidx = oi; bs = os; }
            }
            idxs[r] = bidx; sigs[r] = bs; denom += bs;
            if ((bidx >> 2) == lane) {
                #pragma unroll
                for (int i = 0; i < 4; ++i)
                    if ((bidx & 3) == i) v[i] = -1.0e300;
            }
        }
        denom += 1e-20;
        const size_t n = (size_t)(m0 + wv * 8 + tt);
        #pragma unroll
        for (int r = 0; r < 8; ++r)
            if (lane == r) {
                out[n * 8 + r] = (float)idxs[r];
                out[(size_t)NTOK * 8 + n * 8 + r] = (float)(sigs[r] / denom * 2.5);
            }
    }
}

extern "C" void kernel_launch(void* const* d_in, const int* in_sizes, int n_in,
                              void* d_out, int out_size, void* d_ws, size_t ws_size,
                              hipStream_t stream) {
    const float* X = (const float*)d_in[0];
    const float* W = (const float*)d_in[1];
    const float* bias = (const float*)d_in[2];
    float* out = (float*)d_out;

    const size_t WB = (size_t)NE * H * 2;
    const size_t OFF_W = 65536;
    const size_t OFF_FIX = OFF_W + 2 * WB;
    const size_t FIXB = (size_t)FIXCAP * NE * 8;
    const size_t OFF_LOG = OFF_FIX + FIXB;
    const size_t minlog = (size_t)256 * NE * 4;

    if (ws_size < OFF_LOG + minlog) {
        moe_fb<<<NTOK / 32, 256, 0, stream>>>(X, W, bias, out);
        return;
    }
    int* ws = (int*)d_ws;
    unsigned short* whi = (unsigned short*)((char*)d_ws + OFF_W);
    unsigned short* wlo = whi + (size_t)NE * H;
    double* fixlog = (double*)((char*)d_ws + OFF_FIX);
    float* logits = (float*)((char*)d_ws + OFF_LOG);

    split_w<<<(NE * H) / 1024, 256, 0, stream>>>(W, whi, wlo, ws);

    const size_t avail = ws_size - OFF_LOG;
    size_t full = (size_t)NTOK * NE * 4;
    int CT;
    if (avail >= full) CT = NTOK;
    else {
        CT = (int)(avail / ((size_t)NE * 4));
        CT &= ~255;
    }
    for (int mb0 = 0; mb0 < NTOK; mb0 += CT) {
        int ct = (NTOK - mb0 < CT) ? (NTOK - mb0) : CT;
        gemm3<<<(ct / 64) * 2, 256, 0, stream>>>(X, whi, wlo, logits, mb0);
        route<<<ct / 32, 256, 0, stream>>>(logits, bias, out, ws, FLAGCAP, mb0);
    }
    fix1<<<1024, 256, 0, stream>>>(X, W, ws, fixlog, FIXCAP);
    fix2<<<256, 256, 0, stream>>>(fixlog, bias, out, ws, FIXCAP);
}